// Round 2
// baseline (15837.477 us; speedup 1.0000x reference)
//
#include <hip/hip_runtime.h>
#include <stdint.h>

// GRU: SEQ=512, BATCH=64, IN=512, HID=1024. fp32 in/out, bf16 MFMA internally.
//
// Phase 1: gx = x @ W_ih^T + b_ih  (bf16, stored [512][64][3072] in ws)
// Phase 2: persistent PLAIN-launch kernel, 64 blocks (<=256 CUs so all
//          co-resident); block b owns h-cols [16b,16b+16); per step computes
//          gh r/z/n via 16x16x32 bf16 MFMA with SPLIT h (hi+lo bf16 planes,
//          2 MFMAs per gate) for fp32-like recurrent precision. W_hh r/z
//          fragments persistent in VGPRs. Atomic-counter grid barrier with
//          agent fences (wbl2/inv) for cross-XCD visibility.

#define SEQ    512
#define BATCH  64
#define IN_DIM 512
#define HID    1024
#define G3     3072

typedef __bf16 bf16x8 __attribute__((ext_vector_type(8)));
typedef short  s16x8  __attribute__((ext_vector_type(8)));
typedef float  f32x4  __attribute__((ext_vector_type(4)));

__device__ __forceinline__ float bf2f(unsigned short u) {
    union { unsigned int i; float f; } c; c.i = ((unsigned int)u) << 16; return c.f;
}
__device__ __forceinline__ unsigned short f2bf(float f) {
    union { float f; unsigned int i; } c; c.f = f;
    unsigned int u = c.i;
    u += 0x7fffu + ((u >> 16) & 1u);   // RNE
    return (unsigned short)(u >> 16);
}

// ---------------------------------------------------------------- converts
__global__ void cvt_f32_bf16(const float* __restrict__ in,
                             unsigned short* __restrict__ out, int n) {
    int i = (blockIdx.x * 256 + threadIdx.x) * 4;
    if (i + 3 < n) {
        float4 v = *(const float4*)(in + i);
        ushort4 o;
        o.x = f2bf(v.x); o.y = f2bf(v.y); o.z = f2bf(v.z); o.w = f2bf(v.w);
        *(ushort4*)(out + i) = o;
    }
}

__global__ void init_state(unsigned short* __restrict__ hi,
                           unsigned short* __restrict__ lo,
                           unsigned int* __restrict__ cnt) {
    int i = blockIdx.x * 256 + threadIdx.x;
    if (i < BATCH * HID) { hi[i] = 0; lo[i] = 0; }
    if (i == 0) *cnt = 0u;
}

// ---------------------------------------------------------------- gx GEMM
// C[32768][3072] = A[32768][512] @ W[3072][512]^T + b_ih, operands direct
// from global (bf16, L2/L3-resident), 128x128 block tile, 4 waves of 64x64.
__global__ __launch_bounds__(256) void gx_gemm(
    const unsigned short* __restrict__ xb,
    const unsigned short* __restrict__ wb,
    const float* __restrict__ bih,
    unsigned short* __restrict__ gx) {
    const int lane = threadIdx.x & 63;
    const int wv   = threadIdx.x >> 6;
    const int r    = lane & 15;
    const int quad = lane >> 4;
    const int m0 = blockIdx.x * 128 + (wv & 1) * 64;
    const int n0 = blockIdx.y * 128 + (wv >> 1) * 64;

    f32x4 acc[4][4];
#pragma unroll
    for (int a = 0; a < 4; a++)
#pragma unroll
        for (int b = 0; b < 4; b++) acc[a][b] = (f32x4){0.f, 0.f, 0.f, 0.f};

    const unsigned short* ap[4];
    const unsigned short* bp[4];
#pragma unroll
    for (int mi = 0; mi < 4; mi++)
        ap[mi] = xb + (size_t)(m0 + mi * 16 + r) * IN_DIM + quad * 8;
#pragma unroll
    for (int ni = 0; ni < 4; ni++)
        bp[ni] = wb + (size_t)(n0 + ni * 16 + r) * IN_DIM + quad * 8;

#pragma unroll 4
    for (int kk = 0; kk < IN_DIM / 32; kk++) {
        bf16x8 af[4], bf_[4];
#pragma unroll
        for (int mi = 0; mi < 4; mi++)
            af[mi] = __builtin_bit_cast(bf16x8, *(const s16x8*)(ap[mi] + kk * 32));
#pragma unroll
        for (int ni = 0; ni < 4; ni++)
            bf_[ni] = __builtin_bit_cast(bf16x8, *(const s16x8*)(bp[ni] + kk * 32));
#pragma unroll
        for (int mi = 0; mi < 4; mi++)
#pragma unroll
            for (int ni = 0; ni < 4; ni++)
                acc[mi][ni] = __builtin_amdgcn_mfma_f32_16x16x32_bf16(
                    af[mi], bf_[ni], acc[mi][ni], 0, 0, 0);
    }

#pragma unroll
    for (int ni = 0; ni < 4; ni++) {
        const int col = n0 + ni * 16 + r;
        const float bias = bih[col];
#pragma unroll
        for (int mi = 0; mi < 4; mi++)
#pragma unroll
            for (int i = 0; i < 4; i++) {
                const int row = m0 + mi * 16 + quad * 4 + i;  // C/D m89 layout
                gx[(size_t)row * G3 + col] = f2bf(acc[mi][ni][i] + bias);
            }
    }
}

// ---------------------------------------------------------------- recurrence
// 64 blocks x 256 threads, plain launch (all co-resident). Block b: h-cols
// [16b,16b+16). Wave w: batch rows [16w,16w+16). Split-h: 6 MFMA per k-chunk.
__global__ __launch_bounds__(256, 1) void gru_seq(
    const unsigned short* __restrict__ whb,   // [3072][1024] bf16
    const float* __restrict__ bhh,            // [3072]
    const unsigned short* __restrict__ gxb,   // [512][64][3072] bf16
    unsigned short* __restrict__ hhi0,        // h hi/lo double-buffer planes
    unsigned short* __restrict__ hlo0,
    unsigned short* __restrict__ hhi1,
    unsigned short* __restrict__ hlo1,
    unsigned int* __restrict__ cnt,
    float* __restrict__ out) {
    const int lane = threadIdx.x & 63;
    const int wv   = threadIdx.x >> 6;
    const int r    = lane & 15;
    const int quad = lane >> 4;
    const int J0   = blockIdx.x * 16;

    // Persistent W_hh fragments for r and z gates: 2*32*4 = 256 VGPRs.
    bf16x8 brf[32], bzf[32];
    {
        const unsigned short* wr = whb + (size_t)(J0 + r) * HID + quad * 8;
        const unsigned short* wz = whb + (size_t)(HID + J0 + r) * HID + quad * 8;
#pragma unroll
        for (int kk = 0; kk < 32; kk++) {
            brf[kk] = __builtin_bit_cast(bf16x8, *(const s16x8*)(wr + kk * 32));
            bzf[kk] = __builtin_bit_cast(bf16x8, *(const s16x8*)(wz + kk * 32));
        }
    }
    const unsigned short* wn = whb + (size_t)(2 * HID + J0 + r) * HID + quad * 8;
    const float bhr = bhh[J0 + r];
    const float bhz = bhh[HID + J0 + r];
    const float bhn = bhh[2 * HID + J0 + r];
    const int arow = wv * 16 + r;   // batch row for A fragment (A: m=lane&15)

#pragma unroll 1
    for (int t = 0; t < SEQ; t++) {
        const unsigned short* chi = (t & 1) ? hhi1 : hhi0;
        const unsigned short* clo = (t & 1) ? hlo1 : hlo0;
        unsigned short*       nhi = (t & 1) ? hhi0 : hhi1;
        unsigned short*       nlo = (t & 1) ? hlo0 : hlo1;
        const unsigned short* gxt = gxb + (size_t)t * (BATCH * G3);

        f32x4 aR = {0.f, 0.f, 0.f, 0.f};
        f32x4 aZ = {0.f, 0.f, 0.f, 0.f};
        f32x4 aN = {0.f, 0.f, 0.f, 0.f};
        const unsigned short* hah = chi + (size_t)arow * HID + quad * 8;
        const unsigned short* hal = clo + (size_t)arow * HID + quad * 8;
#pragma unroll
        for (int kk = 0; kk < 32; kk++) {
            bf16x8 ah = __builtin_bit_cast(bf16x8, *(const s16x8*)(hah + kk * 32));
            bf16x8 al = __builtin_bit_cast(bf16x8, *(const s16x8*)(hal + kk * 32));
            bf16x8 bn = __builtin_bit_cast(bf16x8, *(const s16x8*)(wn + kk * 32));
            aR = __builtin_amdgcn_mfma_f32_16x16x32_bf16(ah, brf[kk], aR, 0, 0, 0);
            aR = __builtin_amdgcn_mfma_f32_16x16x32_bf16(al, brf[kk], aR, 0, 0, 0);
            aZ = __builtin_amdgcn_mfma_f32_16x16x32_bf16(ah, bzf[kk], aZ, 0, 0, 0);
            aZ = __builtin_amdgcn_mfma_f32_16x16x32_bf16(al, bzf[kk], aZ, 0, 0, 0);
            aN = __builtin_amdgcn_mfma_f32_16x16x32_bf16(ah, bn,      aN, 0, 0, 0);
            aN = __builtin_amdgcn_mfma_f32_16x16x32_bf16(al, bn,      aN, 0, 0, 0);
        }

#pragma unroll
        for (int i = 0; i < 4; i++) {
            const int row = wv * 16 + quad * 4 + i;   // C/D: row=quad*4+i (m89)
            const int col = J0 + r;                   //      col=lane&15
            const size_t hidx = (size_t)row * HID + col;
            const float xr = bf2f(gxt[(size_t)row * G3 + col]);
            const float xz = bf2f(gxt[(size_t)row * G3 + HID + col]);
            const float xn = bf2f(gxt[(size_t)row * G3 + 2 * HID + col]);
            const float hold = bf2f(chi[hidx]) + bf2f(clo[hidx]);
            const float rg = 1.f / (1.f + __expf(-(xr + aR[i] + bhr)));
            const float zg = 1.f / (1.f + __expf(-(xz + aZ[i] + bhz)));
            const float e2 = __expf(2.f * (xn + rg * (aN[i] + bhn)));
            const float ng = 1.f - 2.f / (e2 + 1.f);
            const float hn = (1.f - zg) * ng + zg * hold;
            const unsigned short uhi = f2bf(hn);
            const unsigned short ulo = f2bf(hn - bf2f(uhi));
            nhi[hidx] = uhi;
            nlo[hidx] = ulo;
            out[(size_t)t * (BATCH * HID) + hidx] = hn;
            if (t == SEQ - 1)
                out[(size_t)SEQ * (BATCH * HID) + hidx] = hn;
        }

        if (t != SEQ - 1) {
            __syncthreads();
            __threadfence();   // release: drain + L2 writeback (agent scope)
            if (threadIdx.x == 0) {
                __hip_atomic_fetch_add(cnt, 1u, __ATOMIC_RELAXED,
                                       __HIP_MEMORY_SCOPE_AGENT);
                const unsigned int target = 64u * (unsigned)(t + 1);
                while (__hip_atomic_load(cnt, __ATOMIC_RELAXED,
                                         __HIP_MEMORY_SCOPE_AGENT) < target) {
                    __builtin_amdgcn_s_sleep(1);
                }
            }
            __syncthreads();
            __threadfence();   // acquire: invalidate L1/L2 for fresh h
        }
    }
}

// ---------------------------------------------------------------- launch
extern "C" void kernel_launch(void* const* d_in, const int* in_sizes, int n_in,
                              void* d_out, int out_size, void* d_ws, size_t ws_size,
                              hipStream_t stream) {
    const float* x   = (const float*)d_in[0];
    const float* Wih = (const float*)d_in[1];
    const float* Whh = (const float*)d_in[2];
    const float* bih = (const float*)d_in[3];
    const float* bhh = (const float*)d_in[4];
    float* out = (float*)d_out;

    char* ws = (char*)d_ws;
    size_t off = 0;
    auto alloc = [&](size_t bytes) {
        char* p = ws + off;
        off += (bytes + 255) & ~(size_t)255;
        return p;
    };
    // small buffers first, big gxb last
    unsigned int*   cnt  = (unsigned int*)alloc(256);
    unsigned short* hhi0 = (unsigned short*)alloc((size_t)BATCH * HID * 2);
    unsigned short* hlo0 = (unsigned short*)alloc((size_t)BATCH * HID * 2);
    unsigned short* hhi1 = (unsigned short*)alloc((size_t)BATCH * HID * 2);
    unsigned short* hlo1 = (unsigned short*)alloc((size_t)BATCH * HID * 2);
    unsigned short* xb   = (unsigned short*)alloc((size_t)SEQ * BATCH * IN_DIM * 2);
    unsigned short* wihb = (unsigned short*)alloc((size_t)G3 * IN_DIM * 2);
    unsigned short* whhb = (unsigned short*)alloc((size_t)G3 * HID * 2);
    unsigned short* gxb  = (unsigned short*)alloc((size_t)SEQ * BATCH * G3 * 2);
    (void)ws_size; (void)in_sizes; (void)n_in; (void)out_size;

    init_state<<<(BATCH * HID + 255) / 256, 256, 0, stream>>>(hhi0, hlo0, cnt);
    cvt_f32_bf16<<<(SEQ * BATCH * IN_DIM / 4) / 256, 256, 0, stream>>>(
        x, xb, SEQ * BATCH * IN_DIM);
    cvt_f32_bf16<<<(G3 * IN_DIM / 4) / 256, 256, 0, stream>>>(Wih, wihb, G3 * IN_DIM);
    cvt_f32_bf16<<<(G3 * HID / 4) / 256, 256, 0, stream>>>(Whh, whhb, G3 * HID);
    gx_gemm<<<dim3(SEQ * BATCH / 128, G3 / 128), 256, 0, stream>>>(
        xb, wihb, bih, gxb);

    gru_seq<<<dim3(64), dim3(256), 0, stream>>>(
        whhb, bhh, gxb, hhi0, hlo0, hhi1, hlo1, cnt, out);
}

// Round 3
// 10448.654 us; speedup vs baseline: 1.5157x; 1.5157x over previous
//
#include <hip/hip_runtime.h>
#include <stdint.h>

// GRU: SEQ=512, BATCH=64, IN=512, HID=1024. fp32 in/out, bf16 MFMA internally.
//
// Phase 1: gx = x @ W_ih^T + b_ih  (bf16, [512][64][3072] in ws)
// Phase 2: persistent plain-launch kernel, 64 blocks (all co-resident);
//          block b owns h-cols [16b,16b+16); per step r/z/n gh via 16x16x32
//          bf16 MFMA with SPLIT h (hi+lo bf16, packed in one u32/elem).
//          Cross-block h exchange goes ONLY through agent-scope (sc0 sc1)
//          atomic load/store -> LLC; NO cache fences, so W_hh/gx stay warm
//          in L1/L2 across all 512 steps (round-1 fences caused 922 MB of
//          HBM refetch = 30 us/step).

#define SEQ    512
#define BATCH  64
#define IN_DIM 512
#define HID    1024
#define G3     3072

typedef __bf16 bf16x8 __attribute__((ext_vector_type(8)));
typedef short  s16x8  __attribute__((ext_vector_type(8)));
typedef float  f32x4  __attribute__((ext_vector_type(4)));
typedef unsigned int u32x4 __attribute__((ext_vector_type(4)));

__device__ __forceinline__ float bf2f(unsigned int u) {
    union { unsigned int i; float f; } c; c.i = u << 16; return c.f;
}
__device__ __forceinline__ unsigned short f2bf(float f) {
    union { float f; unsigned int i; } c; c.f = f;
    unsigned int u = c.i;
    u += 0x7fffu + ((u >> 16) & 1u);   // RNE
    return (unsigned short)(u >> 16);
}

// ---------------------------------------------------------------- converts
__global__ void cvt_f32_bf16(const float* __restrict__ in,
                             unsigned short* __restrict__ out, int n) {
    int i = (blockIdx.x * 256 + threadIdx.x) * 4;
    if (i + 3 < n) {
        float4 v = *(const float4*)(in + i);
        ushort4 o;
        o.x = f2bf(v.x); o.y = f2bf(v.y); o.z = f2bf(v.z); o.w = f2bf(v.w);
        *(ushort4*)(out + i) = o;
    }
}

__global__ void init_state(unsigned int* __restrict__ h0,
                           unsigned int* __restrict__ h1,
                           unsigned int* __restrict__ cnt) {
    int i = blockIdx.x * 256 + threadIdx.x;
    if (i < BATCH * HID) { h0[i] = 0u; h1[i] = 0u; }
    if (i == 0) *cnt = 0u;
}

// ---------------------------------------------------------------- gx GEMM
// C[32768][3072] = A[32768][512] @ W[3072][512]^T + b_ih, operands direct
// from global (bf16, L2/L3-resident), 128x128 block tile, 4 waves of 64x64.
__global__ __launch_bounds__(256) void gx_gemm(
    const unsigned short* __restrict__ xb,
    const unsigned short* __restrict__ wb,
    const float* __restrict__ bih,
    unsigned short* __restrict__ gx) {
    const int lane = threadIdx.x & 63;
    const int wv   = threadIdx.x >> 6;
    const int r    = lane & 15;
    const int quad = lane >> 4;
    const int m0 = blockIdx.x * 128 + (wv & 1) * 64;
    const int n0 = blockIdx.y * 128 + (wv >> 1) * 64;

    f32x4 acc[4][4];
#pragma unroll
    for (int a = 0; a < 4; a++)
#pragma unroll
        for (int b = 0; b < 4; b++) acc[a][b] = (f32x4){0.f, 0.f, 0.f, 0.f};

    const unsigned short* ap[4];
    const unsigned short* bp[4];
#pragma unroll
    for (int mi = 0; mi < 4; mi++)
        ap[mi] = xb + (size_t)(m0 + mi * 16 + r) * IN_DIM + quad * 8;
#pragma unroll
    for (int ni = 0; ni < 4; ni++)
        bp[ni] = wb + (size_t)(n0 + ni * 16 + r) * IN_DIM + quad * 8;

#pragma unroll 4
    for (int kk = 0; kk < IN_DIM / 32; kk++) {
        bf16x8 af[4], bf_[4];
#pragma unroll
        for (int mi = 0; mi < 4; mi++)
            af[mi] = __builtin_bit_cast(bf16x8, *(const s16x8*)(ap[mi] + kk * 32));
#pragma unroll
        for (int ni = 0; ni < 4; ni++)
            bf_[ni] = __builtin_bit_cast(bf16x8, *(const s16x8*)(bp[ni] + kk * 32));
#pragma unroll
        for (int mi = 0; mi < 4; mi++)
#pragma unroll
            for (int ni = 0; ni < 4; ni++)
                acc[mi][ni] = __builtin_amdgcn_mfma_f32_16x16x32_bf16(
                    af[mi], bf_[ni], acc[mi][ni], 0, 0, 0);
    }

#pragma unroll
    for (int ni = 0; ni < 4; ni++) {
        const int col = n0 + ni * 16 + r;
        const float bias = bih[col];
#pragma unroll
        for (int mi = 0; mi < 4; mi++)
#pragma unroll
            for (int i = 0; i < 4; i++) {
                const int row = m0 + mi * 16 + quad * 4 + i;  // C/D m89 layout
                gx[(size_t)row * G3 + col] = f2bf(acc[mi][ni][i] + bias);
            }
    }
}

// ---------------------------------------------------------------- recurrence
// 64 blocks x 256 threads, plain launch (all co-resident). Block b: h-cols
// [16b,16b+16). Wave w: batch rows [16w,16w+16). Split-h: 6 MFMA per k-chunk.
__global__ __launch_bounds__(256, 1) void gru_seq(
    const unsigned short* __restrict__ whb,   // [3072][1024] bf16
    const float* __restrict__ bhh,            // [3072]
    const unsigned short* __restrict__ gxb,   // [512][64][3072] bf16
    unsigned int* __restrict__ h0,            // packed (hi<<16|lo) h, dbuf
    unsigned int* __restrict__ h1,
    unsigned int* __restrict__ cnt,
    float* __restrict__ out) {
    const int lane = threadIdx.x & 63;
    const int wv   = threadIdx.x >> 6;
    const int r    = lane & 15;
    const int quad = lane >> 4;
    const int J0   = blockIdx.x * 16;

    const unsigned short* wr = whb + (size_t)(J0 + r) * HID + quad * 8;
    const unsigned short* wz = whb + (size_t)(HID + J0 + r) * HID + quad * 8;
    const unsigned short* wn = whb + (size_t)(2 * HID + J0 + r) * HID + quad * 8;
    const float bhr = bhh[J0 + r];
    const float bhz = bhh[HID + J0 + r];
    const float bhn = bhh[2 * HID + J0 + r];
    const int arow = wv * 16 + r;   // batch row for A fragment (A: m=lane&15)

#pragma unroll 1
    for (int t = 0; t < SEQ; t++) {
        const unsigned int* cur = (t & 1) ? h1 : h0;
        unsigned int*       nxt = (t & 1) ? h0 : h1;
        const unsigned short* gxt = gxb + (size_t)t * (BATCH * G3);

        // prefetch epilogue gx (HBM) early so MFMA loop hides the latency
        float xr[4], xz[4], xn[4];
#pragma unroll
        for (int i = 0; i < 4; i++) {
            const int row = wv * 16 + quad * 4 + i;
            xr[i] = bf2f(gxt[(size_t)row * G3 + J0 + r]);
            xz[i] = bf2f(gxt[(size_t)row * G3 + HID + J0 + r]);
            xn[i] = bf2f(gxt[(size_t)row * G3 + 2 * HID + J0 + r]);
        }

        f32x4 aR = {0.f, 0.f, 0.f, 0.f};
        f32x4 aZ = {0.f, 0.f, 0.f, 0.f};
        f32x4 aN = {0.f, 0.f, 0.f, 0.f};
        const unsigned int* hrow = cur + (size_t)arow * HID + quad * 8;
#pragma unroll
        for (int kk = 0; kk < 32; kk++) {
            // coherent (LLC) load of 8 packed h words = 4 x 8B relaxed-agent
            unsigned long long q[4];
#pragma unroll
            for (int p = 0; p < 4; p++)
                q[p] = __hip_atomic_load(
                    (const unsigned long long*)(hrow + kk * 32 + 2 * p),
                    __ATOMIC_RELAXED, __HIP_MEMORY_SCOPE_AGENT);
            u32x4 ahw, alw;
#pragma unroll
            for (int p = 0; p < 4; p++) {
                const unsigned int w0 = (unsigned int)q[p];
                const unsigned int w1 = (unsigned int)(q[p] >> 32);
                ahw[p] = __builtin_amdgcn_perm(w1, w0, 0x07060302u); // hi halves
                alw[p] = __builtin_amdgcn_perm(w1, w0, 0x05040100u); // lo halves
            }
            bf16x8 ah = __builtin_bit_cast(bf16x8, ahw);
            bf16x8 al = __builtin_bit_cast(bf16x8, alw);
            bf16x8 fr = __builtin_bit_cast(bf16x8, *(const s16x8*)(wr + kk * 32));
            bf16x8 fz = __builtin_bit_cast(bf16x8, *(const s16x8*)(wz + kk * 32));
            bf16x8 fn = __builtin_bit_cast(bf16x8, *(const s16x8*)(wn + kk * 32));
            aR = __builtin_amdgcn_mfma_f32_16x16x32_bf16(ah, fr, aR, 0, 0, 0);
            aR = __builtin_amdgcn_mfma_f32_16x16x32_bf16(al, fr, aR, 0, 0, 0);
            aZ = __builtin_amdgcn_mfma_f32_16x16x32_bf16(ah, fz, aZ, 0, 0, 0);
            aZ = __builtin_amdgcn_mfma_f32_16x16x32_bf16(al, fz, aZ, 0, 0, 0);
            aN = __builtin_amdgcn_mfma_f32_16x16x32_bf16(ah, fn, aN, 0, 0, 0);
            aN = __builtin_amdgcn_mfma_f32_16x16x32_bf16(al, fn, aN, 0, 0, 0);
        }

#pragma unroll
        for (int i = 0; i < 4; i++) {
            const int row = wv * 16 + quad * 4 + i;   // C/D: row=quad*4+i (m89)
            const int col = J0 + r;                   //      col=lane&15
            const size_t hidx = (size_t)row * HID + col;
            const unsigned int hw = __hip_atomic_load(
                cur + hidx, __ATOMIC_RELAXED, __HIP_MEMORY_SCOPE_AGENT);
            const float hold = bf2f(hw >> 16) + bf2f(hw & 0xffffu);
            const float rg = 1.f / (1.f + __expf(-(xr[i] + aR[i] + bhr)));
            const float zg = 1.f / (1.f + __expf(-(xz[i] + aZ[i] + bhz)));
            const float e2 = __expf(2.f * (xn[i] + rg * (aN[i] + bhn)));
            const float ng = 1.f - 2.f / (e2 + 1.f);
            const float hn = (1.f - zg) * ng + zg * hold;
            const unsigned int uhi = f2bf(hn);
            const unsigned int ulo = f2bf(hn - bf2f(uhi));
            __hip_atomic_store(nxt + hidx, (uhi << 16) | ulo,
                               __ATOMIC_RELAXED, __HIP_MEMORY_SCOPE_AGENT);
            out[(size_t)t * (BATCH * HID) + hidx] = hn;
            if (t == SEQ - 1)
                out[(size_t)SEQ * (BATCH * HID) + hidx] = hn;
        }

        if (t != SEQ - 1) {
            // __syncthreads emits s_waitcnt vmcnt(0) -> coherent h stores are
            // at the LLC before thread0 signals. No cache fences anywhere.
            __syncthreads();
            if (threadIdx.x == 0) {
                __hip_atomic_fetch_add(cnt, 1u, __ATOMIC_RELAXED,
                                       __HIP_MEMORY_SCOPE_AGENT);
                const unsigned int target = 64u * (unsigned)(t + 1);
                while (__hip_atomic_load(cnt, __ATOMIC_RELAXED,
                                         __HIP_MEMORY_SCOPE_AGENT) < target) {
                    __builtin_amdgcn_s_sleep(1);
                }
            }
            __syncthreads();
        }
    }
}

// ---------------------------------------------------------------- launch
extern "C" void kernel_launch(void* const* d_in, const int* in_sizes, int n_in,
                              void* d_out, int out_size, void* d_ws, size_t ws_size,
                              hipStream_t stream) {
    const float* x   = (const float*)d_in[0];
    const float* Wih = (const float*)d_in[1];
    const float* Whh = (const float*)d_in[2];
    const float* bih = (const float*)d_in[3];
    const float* bhh = (const float*)d_in[4];
    float* out = (float*)d_out;

    char* ws = (char*)d_ws;
    size_t off = 0;
    auto alloc = [&](size_t bytes) {
        char* p = ws + off;
        off += (bytes + 255) & ~(size_t)255;
        return p;
    };
    unsigned int*   cnt  = (unsigned int*)alloc(256);
    unsigned int*   h0   = (unsigned int*)alloc((size_t)BATCH * HID * 4);
    unsigned int*   h1   = (unsigned int*)alloc((size_t)BATCH * HID * 4);
    unsigned short* xb   = (unsigned short*)alloc((size_t)SEQ * BATCH * IN_DIM * 2);
    unsigned short* wihb = (unsigned short*)alloc((size_t)G3 * IN_DIM * 2);
    unsigned short* whhb = (unsigned short*)alloc((size_t)G3 * HID * 2);
    unsigned short* gxb  = (unsigned short*)alloc((size_t)SEQ * BATCH * G3 * 2);
    (void)ws_size; (void)in_sizes; (void)n_in; (void)out_size;

    init_state<<<(BATCH * HID + 255) / 256, 256, 0, stream>>>(h0, h1, cnt);
    cvt_f32_bf16<<<(SEQ * BATCH * IN_DIM / 4) / 256, 256, 0, stream>>>(
        x, xb, SEQ * BATCH * IN_DIM);
    cvt_f32_bf16<<<(G3 * IN_DIM / 4) / 256, 256, 0, stream>>>(Wih, wihb, G3 * IN_DIM);
    cvt_f32_bf16<<<(G3 * HID / 4) / 256, 256, 0, stream>>>(Whh, whhb, G3 * HID);
    gx_gemm<<<dim3(SEQ * BATCH / 128, G3 / 128), 256, 0, stream>>>(
        xb, wihb, bih, gxb);

    gru_seq<<<dim3(64), dim3(256), 0, stream>>>(
        whhb, bhh, gxb, h0, h1, cnt, out);
}